// Round 1
// baseline (595.081 us; speedup 1.0000x reference)
//
#include <hip/hip_runtime.h>
#include <stdint.h>

#define RES0 2048
#define RES1 1024
#define HW0 (RES0 * RES0)
#define HW1 (RES1 * RES1)

// 4-bit quant constants: n=16, q=1/16, lo=-15/32
#define QLO (-0.46875f)
#define QSC (0.0625f)

// quantize one float -> code 0..15 (bit-exact vs reference:
// (x - lo)/q == (x - lo)*16 exactly since q is a power of two;
// jnp.round == round-half-even == rintf in RN mode)
__device__ __forceinline__ uint32_t qcode(float x) {
    float t = (x - QLO) * 16.0f;
    float r = rintf(t);
    r = fminf(fmaxf(r, 0.0f), 15.0f);
    return (uint32_t)(int)r;
}

__device__ __forceinline__ float dq(uint32_t packed, int c) {
    return (float)((packed >> (4 * c)) & 15u) * QSC + QLO;
}

// Pack both grids: 8 channels x 4-bit codes per texel -> one uint32 per texel.
// Each thread handles 4 consecutive texels (float4 per channel plane, uint4 out).
__global__ __launch_bounds__(256) void pack_both_kernel(
    const float4* __restrict__ g0, const float4* __restrict__ g1,
    uint4* __restrict__ p0, uint4* __restrict__ p1)
{
    const int i = blockIdx.x * 256 + threadIdx.x;
    const int n0 = HW0 / 4;
    const int n1 = HW1 / 4;
    if (i < n0) {
        uint4 r = make_uint4(0u, 0u, 0u, 0u);
#pragma unroll
        for (int c = 0; c < 8; ++c) {
            float4 v = g0[(size_t)c * n0 + i];
            r.x |= qcode(v.x) << (4 * c);
            r.y |= qcode(v.y) << (4 * c);
            r.z |= qcode(v.z) << (4 * c);
            r.w |= qcode(v.w) << (4 * c);
        }
        p0[i] = r;
    } else {
        const int j = i - n0;
        if (j < n1) {
            uint4 r = make_uint4(0u, 0u, 0u, 0u);
#pragma unroll
            for (int c = 0; c < 8; ++c) {
                float4 v = g1[(size_t)c * n1 + j];
                r.x |= qcode(v.x) << (4 * c);
                r.y |= qcode(v.y) << (4 * c);
                r.z |= qcode(v.z) << (4 * c);
                r.w |= qcode(v.w) << (4 * c);
            }
            p1[j] = r;
        }
    }
}

__global__ __launch_bounds__(256) void sample_kernel(
    const float2* __restrict__ uv,
    const uint32_t* __restrict__ p0,
    const uint32_t* __restrict__ p1,
    float* __restrict__ out, int n)
{
#pragma clang fp contract(off)
    const int i = blockIdx.x * 256 + threadIdx.x;
    if (i >= n) return;
    const float2 u = uv[i];

    float o[40];

    // ---- G0: 4-neighbor gather (no interpolation), concat 4x8 channels ----
    float px = u.x * 2048.0f; px = px - 0.5f;
    float py = u.y * 2048.0f; py = py - 0.5f;
    float fx = fminf(fmaxf(floorf(px), 0.0f), 2046.0f);
    float fy = fminf(fmaxf(floorf(py), 0.0f), 2046.0f);
    const int x0 = (int)fx;
    const int y0 = (int)fy;
    const uint32_t* row = p0 + y0 * RES0 + x0;
    const uint32_t t00 = row[0];
    const uint32_t t01 = row[1];
    const uint32_t t10 = row[RES0];
    const uint32_t t11 = row[RES0 + 1];
#pragma unroll
    for (int c = 0; c < 8; ++c) {
        o[c]      = dq(t00, c);
        o[8 + c]  = dq(t01, c);
        o[16 + c] = dq(t10, c);
        o[24 + c] = dq(t11, c);
    }

    // ---- G1: bilinear grid_sample, align_corners=False, zeros padding ----
    const float gx = u.x * 2.0f - 1.0f;
    const float gy = u.y * 2.0f - 1.0f;
    float ix = (gx + 1.0f) * 0.5f; ix = ix * 1024.0f; ix = ix - 0.5f;
    float iy = (gy + 1.0f) * 0.5f; iy = iy * 1024.0f; iy = iy - 0.5f;
    const float x0f = floorf(ix);
    const float y0f = floorf(iy);
    const float wx1 = ix - x0f;
    const float wy1 = iy - y0f;
    const float wx0 = 1.0f - wx1;
    const float wy0 = 1.0f - wy1;
    const int jx0 = (int)x0f, jy0 = (int)y0f;
    const int jx1 = jx0 + 1,  jy1 = jy0 + 1;
    const bool vx0 = (jx0 >= 0) && (jx0 <= RES1 - 1);
    const bool vx1 = (jx1 >= 0) && (jx1 <= RES1 - 1);
    const bool vy0 = (jy0 >= 0) && (jy0 <= RES1 - 1);
    const bool vy1 = (jy1 >= 0) && (jy1 <= RES1 - 1);
    const int cx0 = min(max(jx0, 0), RES1 - 1);
    const int cx1 = min(max(jx1, 0), RES1 - 1);
    const int cy0 = min(max(jy0, 0), RES1 - 1);
    const int cy1 = min(max(jy1, 0), RES1 - 1);
    const uint32_t s00 = p1[cy0 * RES1 + cx0];
    const uint32_t s10 = p1[cy0 * RES1 + cx1];
    const uint32_t s01 = p1[cy1 * RES1 + cx0];
    const uint32_t s11 = p1[cy1 * RES1 + cx1];
    const float w00 = (vx0 && vy0) ? wx0 * wy0 : 0.0f;
    const float w10 = (vx1 && vy0) ? wx1 * wy0 : 0.0f;
    const float w01 = (vx0 && vy1) ? wx0 * wy1 : 0.0f;
    const float w11 = (vx1 && vy1) ? wx1 * wy1 : 0.0f;
#pragma unroll
    for (int c = 0; c < 8; ++c) {
        // reference sum order: ((t(x0,y0) + t(x1,y0)) + t(x0,y1)) + t(x1,y1)
        float a = dq(s00, c) * w00 + dq(s10, c) * w10;
        a = a + dq(s01, c) * w01;
        a = a + dq(s11, c) * w11;
        o[32 + c] = a;
    }

    // ---- store 40 floats (160 B, 16B-aligned) as 10 x float4 ----
    float4* dst = (float4*)(out + (size_t)i * 40);
#pragma unroll
    for (int k = 0; k < 10; ++k) {
        dst[k] = make_float4(o[4 * k], o[4 * k + 1], o[4 * k + 2], o[4 * k + 3]);
    }
}

// Fallback (only if ws_size is too small for the packed maps): gather raw
// grids with on-the-fly fake-quant. Slow but correct.
__device__ __forceinline__ float fq1(float x) {
    float r = fminf(fmaxf(rintf((x - QLO) * 16.0f), 0.0f), 15.0f);
    return r * QSC + QLO;
}

__global__ __launch_bounds__(256) void sample_direct_kernel(
    const float2* __restrict__ uv,
    const float* __restrict__ g0,
    const float* __restrict__ g1,
    float* __restrict__ out, int n)
{
#pragma clang fp contract(off)
    const int i = blockIdx.x * 256 + threadIdx.x;
    if (i >= n) return;
    const float2 u = uv[i];
    float o[40];

    float px = u.x * 2048.0f; px = px - 0.5f;
    float py = u.y * 2048.0f; py = py - 0.5f;
    const int x0 = (int)fminf(fmaxf(floorf(px), 0.0f), 2046.0f);
    const int y0 = (int)fminf(fmaxf(floorf(py), 0.0f), 2046.0f);
#pragma unroll
    for (int c = 0; c < 8; ++c) {
        const float* pl = g0 + (size_t)c * HW0;
        o[c]      = fq1(pl[y0 * RES0 + x0]);
        o[8 + c]  = fq1(pl[y0 * RES0 + x0 + 1]);
        o[16 + c] = fq1(pl[(y0 + 1) * RES0 + x0]);
        o[24 + c] = fq1(pl[(y0 + 1) * RES0 + x0 + 1]);
    }

    const float gx = u.x * 2.0f - 1.0f;
    const float gy = u.y * 2.0f - 1.0f;
    float ix = (gx + 1.0f) * 0.5f; ix = ix * 1024.0f; ix = ix - 0.5f;
    float iy = (gy + 1.0f) * 0.5f; iy = iy * 1024.0f; iy = iy - 0.5f;
    const float x0f = floorf(ix), y0f = floorf(iy);
    const float wx1 = ix - x0f, wy1 = iy - y0f;
    const float wx0 = 1.0f - wx1, wy0 = 1.0f - wy1;
    const int jx0 = (int)x0f, jy0 = (int)y0f;
    const int jx1 = jx0 + 1, jy1 = jy0 + 1;
    const bool vx0 = (jx0 >= 0) && (jx0 < RES1);
    const bool vx1 = (jx1 >= 0) && (jx1 < RES1);
    const bool vy0 = (jy0 >= 0) && (jy0 < RES1);
    const bool vy1 = (jy1 >= 0) && (jy1 < RES1);
    const int cx0 = min(max(jx0, 0), RES1 - 1);
    const int cx1 = min(max(jx1, 0), RES1 - 1);
    const int cy0 = min(max(jy0, 0), RES1 - 1);
    const int cy1 = min(max(jy1, 0), RES1 - 1);
    const float w00 = (vx0 && vy0) ? wx0 * wy0 : 0.0f;
    const float w10 = (vx1 && vy0) ? wx1 * wy0 : 0.0f;
    const float w01 = (vx0 && vy1) ? wx0 * wy1 : 0.0f;
    const float w11 = (vx1 && vy1) ? wx1 * wy1 : 0.0f;
#pragma unroll
    for (int c = 0; c < 8; ++c) {
        const float* pl = g1 + (size_t)c * HW1;
        float a = fq1(pl[cy0 * RES1 + cx0]) * w00 + fq1(pl[cy0 * RES1 + cx1]) * w10;
        a = a + fq1(pl[cy1 * RES1 + cx0]) * w01;
        a = a + fq1(pl[cy1 * RES1 + cx1]) * w11;
        o[32 + c] = a;
    }

    float4* dst = (float4*)(out + (size_t)i * 40);
#pragma unroll
    for (int k = 0; k < 10; ++k) {
        dst[k] = make_float4(o[4 * k], o[4 * k + 1], o[4 * k + 2], o[4 * k + 3]);
    }
}

extern "C" void kernel_launch(void* const* d_in, const int* in_sizes, int n_in,
                              void* d_out, int out_size, void* d_ws, size_t ws_size,
                              hipStream_t stream)
{
    const float* uv = (const float*)d_in[0];
    const float* g0 = (const float*)d_in[1];
    const float* g1 = (const float*)d_in[2];
    float* out = (float*)d_out;
    const int n = in_sizes[0] / 2;  // uv is [N,2]

    const size_t need = (size_t)(HW0 + HW1) * sizeof(uint32_t);  // ~21 MB
    if (ws_size >= need) {
        uint32_t* p0 = (uint32_t*)d_ws;
        uint32_t* p1 = p0 + HW0;
        const int pack_threads = (HW0 + HW1) / 4;  // 4 texels per thread
        pack_both_kernel<<<(pack_threads + 255) / 256, 256, 0, stream>>>(
            (const float4*)g0, (const float4*)g1, (uint4*)p0, (uint4*)p1);
        sample_kernel<<<(n + 255) / 256, 256, 0, stream>>>(
            (const float2*)uv, p0, p1, out, n);
    } else {
        sample_direct_kernel<<<(n + 255) / 256, 256, 0, stream>>>(
            (const float2*)uv, g0, g1, out, n);
    }
}

// Round 2
// 549.573 us; speedup vs baseline: 1.0828x; 1.0828x over previous
//
#include <hip/hip_runtime.h>
#include <stdint.h>

#define RES0 2048
#define RES1 1024
#define HW0 (RES0 * RES0)
#define HW1 (RES1 * RES1)
#define NQ0 ((RES0 / 2) * (RES0 / 2))  // quads in g0 map: 1M
#define NQ1 ((RES1 / 2) * (RES1 / 2))  // quads in g1 map: 256K

// 4-bit quant constants: n=16, q=1/16, lo=-15/32
#define QLO (-0.46875f)
#define QSC (0.0625f)

// quantize one float -> code 0..15 (bit-exact vs reference: (x-lo)/q ==
// (x-lo)*16 exactly since q is 2^-4; jnp.round == half-even == rintf)
__device__ __forceinline__ uint32_t qcode(float x) {
    float t = (x - QLO) * 16.0f;
    float r = rintf(t);
    r = fminf(fmaxf(r, 0.0f), 15.0f);
    return (uint32_t)(int)r;
}

__device__ __forceinline__ float dq(uint32_t packed, int c) {
    return (float)((packed >> (4 * c)) & 15u) * QSC + QLO;
}

// Fetch texel (x,y) from a quad-packed map: each uint4 = 2x2 texel block
//   Q.x=(2qx,2qy) Q.y=(2qx+1,2qy) Q.z=(2qx,2qy+1) Q.w=(2qx+1,2qy+1)
__device__ __forceinline__ uint32_t texel_fetch(const uint4* __restrict__ map,
                                                int pitch_q, int x, int y) {
    uint4 Q = map[(y >> 1) * pitch_q + (x >> 1)];
    uint32_t lo = (x & 1) ? Q.y : Q.x;
    uint32_t hi = (x & 1) ? Q.w : Q.z;
    return (y & 1) ? hi : lo;
}

// Pack both grids into quad layout. One thread per quad; reads 8 channels x
// 2 rows as float2 (fully coalesced), writes one uint4 (coalesced).
__global__ __launch_bounds__(256) void pack_quads_kernel(
    const float2* __restrict__ g0, const float2* __restrict__ g1,
    uint4* __restrict__ q0, uint4* __restrict__ q1)
{
    const int i = blockIdx.x * 256 + threadIdx.x;
    if (i < NQ0) {
        const int qx = i & 1023;
        const int qy = i >> 10;
        uint4 r = make_uint4(0u, 0u, 0u, 0u);
#pragma unroll
        for (int c = 0; c < 8; ++c) {
            float2 r0 = g0[(size_t)c * (HW0 / 2) + (size_t)(2 * qy) * 1024 + qx];
            float2 r1 = g0[(size_t)c * (HW0 / 2) + (size_t)(2 * qy + 1) * 1024 + qx];
            r.x |= qcode(r0.x) << (4 * c);
            r.y |= qcode(r0.y) << (4 * c);
            r.z |= qcode(r1.x) << (4 * c);
            r.w |= qcode(r1.y) << (4 * c);
        }
        q0[i] = r;
    } else {
        const int j = i - NQ0;
        if (j < NQ1) {
            const int qx = j & 511;
            const int qy = j >> 9;
            uint4 r = make_uint4(0u, 0u, 0u, 0u);
#pragma unroll
            for (int c = 0; c < 8; ++c) {
                float2 r0 = g1[(size_t)c * (HW1 / 2) + (size_t)(2 * qy) * 512 + qx];
                float2 r1 = g1[(size_t)c * (HW1 / 2) + (size_t)(2 * qy + 1) * 512 + qx];
                r.x |= qcode(r0.x) << (4 * c);
                r.y |= qcode(r0.y) << (4 * c);
                r.z |= qcode(r1.x) << (4 * c);
                r.w |= qcode(r1.y) << (4 * c);
            }
            q1[j] = r;
        }
    }
}

__global__ __launch_bounds__(256) void sample_kernel(
    const float2* __restrict__ uv,
    const uint4* __restrict__ q0,
    const uint4* __restrict__ q1,
    float* __restrict__ out, int n)
{
#pragma clang fp contract(off)
    // float4 staging, stride 11 (pad) per thread: write-phase banks 2-way (free)
    __shared__ float4 lds4[256 * 11];  // 45056 B
    const int t = threadIdx.x;
    const int i = blockIdx.x * 256 + t;

    if (i < n) {
        const float2 u = uv[i];

        // ---- G0: 4-neighbor gather (no interpolation), 4x8 channels ----
        float px = u.x * 2048.0f; px = px - 0.5f;
        float py = u.y * 2048.0f; py = py - 0.5f;
        float fx = fminf(fmaxf(floorf(px), 0.0f), 2046.0f);
        float fy = fminf(fmaxf(floorf(py), 0.0f), 2046.0f);
        const int x0 = (int)fx;
        const int y0 = (int)fy;
        const uint32_t t00 = texel_fetch(q0, 1024, x0,     y0);
        const uint32_t t01 = texel_fetch(q0, 1024, x0 + 1, y0);
        const uint32_t t10 = texel_fetch(q0, 1024, x0,     y0 + 1);
        const uint32_t t11 = texel_fetch(q0, 1024, x0 + 1, y0 + 1);

        // ---- G1 indices/weights (bilinear, align_corners=False, zeros pad) ----
        const float gx = u.x * 2.0f - 1.0f;
        const float gy = u.y * 2.0f - 1.0f;
        float ix = (gx + 1.0f) * 0.5f; ix = ix * 1024.0f; ix = ix - 0.5f;
        float iy = (gy + 1.0f) * 0.5f; iy = iy * 1024.0f; iy = iy - 0.5f;
        const float x0f = floorf(ix);
        const float y0f = floorf(iy);
        const float wx1 = ix - x0f;
        const float wy1 = iy - y0f;
        const float wx0 = 1.0f - wx1;
        const float wy0 = 1.0f - wy1;
        const int jx0 = (int)x0f, jy0 = (int)y0f;
        const int jx1 = jx0 + 1,  jy1 = jy0 + 1;
        const bool vx0 = (jx0 >= 0) && (jx0 <= RES1 - 1);
        const bool vx1 = (jx1 >= 0) && (jx1 <= RES1 - 1);
        const bool vy0 = (jy0 >= 0) && (jy0 <= RES1 - 1);
        const bool vy1 = (jy1 >= 0) && (jy1 <= RES1 - 1);
        const int cx0 = min(max(jx0, 0), RES1 - 1);
        const int cx1 = min(max(jx1, 0), RES1 - 1);
        const int cy0 = min(max(jy0, 0), RES1 - 1);
        const int cy1 = min(max(jy1, 0), RES1 - 1);
        const uint32_t s00 = texel_fetch(q1, 512, cx0, cy0);
        const uint32_t s10 = texel_fetch(q1, 512, cx1, cy0);
        const uint32_t s01 = texel_fetch(q1, 512, cx0, cy1);
        const uint32_t s11 = texel_fetch(q1, 512, cx1, cy1);
        const float w00 = (vx0 && vy0) ? wx0 * wy0 : 0.0f;
        const float w10 = (vx1 && vy0) ? wx1 * wy0 : 0.0f;
        const float w01 = (vx0 && vy1) ? wx0 * wy1 : 0.0f;
        const float w11 = (vx1 && vy1) ? wx1 * wy1 : 0.0f;

        // ---- stage 40 floats as 10 float4s into LDS ----
        float4* my = &lds4[t * 11];
        my[0] = make_float4(dq(t00, 0), dq(t00, 1), dq(t00, 2), dq(t00, 3));
        my[1] = make_float4(dq(t00, 4), dq(t00, 5), dq(t00, 6), dq(t00, 7));
        my[2] = make_float4(dq(t01, 0), dq(t01, 1), dq(t01, 2), dq(t01, 3));
        my[3] = make_float4(dq(t01, 4), dq(t01, 5), dq(t01, 6), dq(t01, 7));
        my[4] = make_float4(dq(t10, 0), dq(t10, 1), dq(t10, 2), dq(t10, 3));
        my[5] = make_float4(dq(t10, 4), dq(t10, 5), dq(t10, 6), dq(t10, 7));
        my[6] = make_float4(dq(t11, 0), dq(t11, 1), dq(t11, 2), dq(t11, 3));
        my[7] = make_float4(dq(t11, 4), dq(t11, 5), dq(t11, 6), dq(t11, 7));

        float a[8];
#pragma unroll
        for (int c = 0; c < 8; ++c) {
            // reference sum order: ((t00 + t10) + t01) + t11 taps
            float s = dq(s00, c) * w00 + dq(s10, c) * w10;
            s = s + dq(s01, c) * w01;
            s = s + dq(s11, c) * w11;
            a[c] = s;
        }
        my[8] = make_float4(a[0], a[1], a[2], a[3]);
        my[9] = make_float4(a[4], a[5], a[6], a[7]);
    }
    __syncthreads();

    // ---- coalesced flush: 2560 contiguous float4s per block ----
    const int blk_base = blockIdx.x * 256;
    const int nblk = min(n - blk_base, 256);
    const int total = nblk * 10;
    float4* dst = (float4*)(out + (size_t)blk_base * 40);
#pragma unroll
    for (int j = 0; j < 10; ++j) {
        const int e = j * 256 + t;
        if (e < total) {
            const int p = e / 10;
            const int k = e - p * 10;
            dst[e] = lds4[p * 11 + k];
        }
    }
}

// Fallback (ws too small for packed maps): direct gather with on-the-fly
// fake-quant. Slow but correct.
__device__ __forceinline__ float fq1(float x) {
    float r = fminf(fmaxf(rintf((x - QLO) * 16.0f), 0.0f), 15.0f);
    return r * QSC + QLO;
}

__global__ __launch_bounds__(256) void sample_direct_kernel(
    const float2* __restrict__ uv,
    const float* __restrict__ g0,
    const float* __restrict__ g1,
    float* __restrict__ out, int n)
{
#pragma clang fp contract(off)
    const int i = blockIdx.x * 256 + threadIdx.x;
    if (i >= n) return;
    const float2 u = uv[i];
    float o[40];

    float px = u.x * 2048.0f; px = px - 0.5f;
    float py = u.y * 2048.0f; py = py - 0.5f;
    const int x0 = (int)fminf(fmaxf(floorf(px), 0.0f), 2046.0f);
    const int y0 = (int)fminf(fmaxf(floorf(py), 0.0f), 2046.0f);
#pragma unroll
    for (int c = 0; c < 8; ++c) {
        const float* pl = g0 + (size_t)c * HW0;
        o[c]      = fq1(pl[y0 * RES0 + x0]);
        o[8 + c]  = fq1(pl[y0 * RES0 + x0 + 1]);
        o[16 + c] = fq1(pl[(y0 + 1) * RES0 + x0]);
        o[24 + c] = fq1(pl[(y0 + 1) * RES0 + x0 + 1]);
    }

    const float gx = u.x * 2.0f - 1.0f;
    const float gy = u.y * 2.0f - 1.0f;
    float ix = (gx + 1.0f) * 0.5f; ix = ix * 1024.0f; ix = ix - 0.5f;
    float iy = (gy + 1.0f) * 0.5f; iy = iy * 1024.0f; iy = iy - 0.5f;
    const float x0f = floorf(ix), y0f = floorf(iy);
    const float wx1 = ix - x0f, wy1 = iy - y0f;
    const float wx0 = 1.0f - wx1, wy0 = 1.0f - wy1;
    const int jx0 = (int)x0f, jy0 = (int)y0f;
    const int jx1 = jx0 + 1, jy1 = jy0 + 1;
    const bool vx0 = (jx0 >= 0) && (jx0 < RES1);
    const bool vx1 = (jx1 >= 0) && (jx1 < RES1);
    const bool vy0 = (jy0 >= 0) && (jy0 < RES1);
    const bool vy1 = (jy1 >= 0) && (jy1 < RES1);
    const int cx0 = min(max(jx0, 0), RES1 - 1);
    const int cx1 = min(max(jx1, 0), RES1 - 1);
    const int cy0 = min(max(jy0, 0), RES1 - 1);
    const int cy1 = min(max(jy1, 0), RES1 - 1);
    const float w00 = (vx0 && vy0) ? wx0 * wy0 : 0.0f;
    const float w10 = (vx1 && vy0) ? wx1 * wy0 : 0.0f;
    const float w01 = (vx0 && vy1) ? wx0 * wy1 : 0.0f;
    const float w11 = (vx1 && vy1) ? wx1 * wy1 : 0.0f;
#pragma unroll
    for (int c = 0; c < 8; ++c) {
        const float* pl = g1 + (size_t)c * HW1;
        float a = fq1(pl[cy0 * RES1 + cx0]) * w00 + fq1(pl[cy0 * RES1 + cx1]) * w10;
        a = a + fq1(pl[cy1 * RES1 + cx0]) * w01;
        a = a + fq1(pl[cy1 * RES1 + cx1]) * w11;
        o[32 + c] = a;
    }

    float4* dst = (float4*)(out + (size_t)i * 40);
#pragma unroll
    for (int k = 0; k < 10; ++k) {
        dst[k] = make_float4(o[4 * k], o[4 * k + 1], o[4 * k + 2], o[4 * k + 3]);
    }
}

extern "C" void kernel_launch(void* const* d_in, const int* in_sizes, int n_in,
                              void* d_out, int out_size, void* d_ws, size_t ws_size,
                              hipStream_t stream)
{
    const float* uv = (const float*)d_in[0];
    const float* g0 = (const float*)d_in[1];
    const float* g1 = (const float*)d_in[2];
    float* out = (float*)d_out;
    const int n = in_sizes[0] / 2;  // uv is [N,2]

    const size_t need = (size_t)(NQ0 + NQ1) * sizeof(uint4);  // ~21 MB
    if (ws_size >= need) {
        uint4* q0 = (uint4*)d_ws;
        uint4* q1 = q0 + NQ0;
        const int pack_threads = NQ0 + NQ1;
        pack_quads_kernel<<<(pack_threads + 255) / 256, 256, 0, stream>>>(
            (const float2*)g0, (const float2*)g1, q0, q1);
        sample_kernel<<<(n + 255) / 256, 256, 0, stream>>>(
            (const float2*)uv, q0, q1, out, n);
    } else {
        sample_direct_kernel<<<(n + 255) / 256, 256, 0, stream>>>(
            (const float2*)uv, g0, g1, out, n);
    }
}